// Round 2
// baseline (582.779 us; speedup 1.0000x reference)
//
#include <hip/hip_runtime.h>
#include <hip/hip_cooperative_groups.h>
#include <math.h>

namespace cg = cooperative_groups;

#define NN 2048
#define CC 128
#define HH 8
#define DD 16
#define NKEY 128
#define INFV 1e8f
#define NPR ((long)NN * CC / 4)
#define NCPTOT (NPR + (long)NN * NN * 4)

__device__ __forceinline__ float sigm(float x) { return 1.f / (1.f + expf(-x)); }

struct Args {
  const float *atom_single, *atom_proj, *atom_pair, *mask;
  const float *a_sln_w, *a_gate_w, *a_gate_b, *a_skip_w;
  const float *wq, *bq, *wk, *wv, *wg, *bg, *wo, *bo;
  const float *lnz_w, *lnz_b, *wz, *wog, *bog;
  const float *t_sln_w, *t_gate_w, *t_gate_b, *t_skip_w;
  const float *w_sw, *w_hid, *w_out, *t_wog, *t_bog;
  float *out;
  float *s_ln_a, *s_ln_t, *ln_as, *a_mat, *qm, *km, *vm, *gm, *ogm,
        *single2, *ln_a2, *t_mat, *hidden, *bias;
  long cut[10];
};

// ---------------------------------------------------------------------------
// Passthrough copy slice: stage s copies float4 range [cut[s], cut[s+1])
// across nb blocks (rb = this block's index within the copy set).
// ---------------------------------------------------------------------------
__device__ __forceinline__ void copy_stage(const Args& a, int s, int rb, int nb, int tid) {
  long c0 = a.cut[s], c1 = a.cut[s + 1];
  const float4* proj4 = (const float4*)a.atom_proj;
  const float4* pair4 = (const float4*)a.atom_pair;
  float4* dst = (float4*)(a.out + (long)NN * CC);
  long stride = (long)nb * 256;
  long i = c0 + (long)rb * 256 + tid;
  for (; i + 3 * stride < c1; i += 4 * stride) {
    long i1 = i + stride, i2 = i + 2 * stride, i3 = i + 3 * stride;
    float4 x0 = (i  < NPR) ? proj4[i]  : pair4[i  - NPR];
    float4 x1 = (i1 < NPR) ? proj4[i1] : pair4[i1 - NPR];
    float4 x2 = (i2 < NPR) ? proj4[i2] : pair4[i2 - NPR];
    float4 x3 = (i3 < NPR) ? proj4[i3] : pair4[i3 - NPR];
    dst[i] = x0; dst[i1] = x1; dst[i2] = x2; dst[i3] = x3;
  }
  for (; i < c1; i += stride) dst[i] = (i < NPR) ? proj4[i] : pair4[i - NPR];
}

// ---------------------------------------------------------------------------
// Dual-GEMM 64x64 tile, BK=32: acc1 = A1@B1 (K1), acc2 = A2@B2 (K2<=K1).
// ---------------------------------------------------------------------------
template <bool HAS2>
__device__ __forceinline__ void gpair(float* sm, int tid,
    const float* __restrict__ A1, const float* __restrict__ B1, int lda1, int ldb1, int K1,
    const float* __restrict__ A2, const float* __restrict__ B2, int lda2, int ldb2, int K2,
    int r0, int c0, float acc1[4][4], float acc2[4][4]) {
  float* A1s = sm;            // [32][68]
  float* B1s = sm + 2176;
  float* A2s = sm + 4352;
  float* B2s = sm + 6528;
  int tr = (tid >> 4) * 4, tc = (tid & 15) * 4;
  int nk = K1 / 32;
  for (int kt = 0; kt < nk; ++kt) {
    int kb = kt * 32;
    bool two = false;
    if constexpr (HAS2) two = (kb < K2);
    __syncthreads();
    for (int i = tid; i < 32 * 64; i += 256) {
      int r = i >> 5, k = i & 31;
      A1s[k * 68 + r] = A1[(long)(r0 + r) * lda1 + kb + k];
      if (two) A2s[k * 68 + r] = A2[(long)(r0 + r) * lda2 + kb + k];
    }
    for (int i = tid; i < 32 * 64; i += 256) {
      int k = i >> 6, c = i & 63;
      B1s[k * 68 + c] = B1[(long)(kb + k) * ldb1 + c0 + c];
      if (two) B2s[k * 68 + c] = B2[(long)(kb + k) * ldb2 + c0 + c];
    }
    __syncthreads();
    if (two) {
      for (int k = 0; k < 32; ++k) {
        float4 a1 = *(const float4*)&A1s[k * 68 + tr];
        float4 b1 = *(const float4*)&B1s[k * 68 + tc];
        float4 a2 = *(const float4*)&A2s[k * 68 + tr];
        float4 b2 = *(const float4*)&B2s[k * 68 + tc];
        float a1v[4] = {a1.x, a1.y, a1.z, a1.w};
        float b1v[4] = {b1.x, b1.y, b1.z, b1.w};
        float a2v[4] = {a2.x, a2.y, a2.z, a2.w};
        float b2v[4] = {b2.x, b2.y, b2.z, b2.w};
#pragma unroll
        for (int i = 0; i < 4; ++i)
#pragma unroll
          for (int j = 0; j < 4; ++j) {
            acc1[i][j] = fmaf(a1v[i], b1v[j], acc1[i][j]);
            acc2[i][j] = fmaf(a2v[i], b2v[j], acc2[i][j]);
          }
      }
    } else {
      for (int k = 0; k < 32; ++k) {
        float4 a1 = *(const float4*)&A1s[k * 68 + tr];
        float4 b1 = *(const float4*)&B1s[k * 68 + tc];
        float a1v[4] = {a1.x, a1.y, a1.z, a1.w};
        float b1v[4] = {b1.x, b1.y, b1.z, b1.w};
#pragma unroll
        for (int i = 0; i < 4; ++i)
#pragma unroll
          for (int j = 0; j < 4; ++j) acc1[i][j] = fmaf(a1v[i], b1v[j], acc1[i][j]);
      }
    }
  }
}

// ---------------------------------------------------------------------------
// Stage bodies
// ---------------------------------------------------------------------------
__device__ __forceinline__ void bias_stage(const Args& a, int bid, int tid, float* sm) {
  float* swz = sm;          // 128
  float* swn = sm + 128;    // 16
  float* sbn = sm + 144;    // 16
  if (tid < 128) swz[tid] = a.wz[tid];
  else if (tid < 144) swn[tid - 128] = a.lnz_w[tid - 128];
  else if (tid < 160) sbn[tid - 144] = a.lnz_b[tid - 144];
  __syncthreads();
  for (int e = bid * 256 + tid; e < NN * NKEY; e += 96 * 256) {
    int q = e >> 7, kk = e & 127;
    int k = (q >> 5) * 32 - 48 + kk;
    float o[HH];
    if (k >= 0 && k < NN) {
      const float4* p = (const float4*)(a.atom_pair + ((long)q * NN + k) * 16);
      float4 x0 = p[0], x1 = p[1], x2 = p[2], x3 = p[3];
      float x[16] = {x0.x, x0.y, x0.z, x0.w, x1.x, x1.y, x1.z, x1.w,
                     x2.x, x2.y, x2.z, x2.w, x3.x, x3.y, x3.z, x3.w};
      float s = 0.f, ss = 0.f;
#pragma unroll
      for (int c = 0; c < 16; ++c) { s += x[c]; ss += x[c] * x[c]; }
      float mu = s * (1.f / 16.f);
      float r = rsqrtf(ss * (1.f / 16.f) - mu * mu + 1e-5f);
#pragma unroll
      for (int h = 0; h < HH; ++h) o[h] = 0.f;
#pragma unroll
      for (int c = 0; c < 16; ++c) {
        float y = (x[c] - mu) * r * swn[c] + sbn[c];
#pragma unroll
        for (int h = 0; h < HH; ++h) o[h] = fmaf(y, swz[c * HH + h], o[h]);
      }
      float mb = INFV * (a.mask[k] - 1.f);
#pragma unroll
      for (int h = 0; h < HH; ++h) o[h] += mb;
    } else {
#pragma unroll
      for (int h = 0; h < HH; ++h) o[h] = -INFV;
    }
#pragma unroll
    for (int h = 0; h < HH; ++h) a.bias[(long)h * NN * NKEY + e] = o[h];
  }
}

__device__ __forceinline__ void ln1_stage(const Args& a, int lb, int tid) {
  int base = lb * 64;
  int lane = tid & 63;
  for (int r = base + (tid >> 6); r < base + 64; r += 4) {
    {
      float2 v = *(const float2*)(a.atom_single + (long)r * CC + lane * 2);
      float s = v.x + v.y, ss = v.x * v.x + v.y * v.y;
#pragma unroll
      for (int m = 1; m < 64; m <<= 1) { s += __shfl_xor(s, m); ss += __shfl_xor(ss, m); }
      float mu = s * (1.f / CC);
      float rr = rsqrtf(ss * (1.f / CC) - mu * mu + 1e-5f);
      *(float2*)(a.ln_as + (long)r * CC + lane * 2) =
          make_float2((v.x - mu) * rr, (v.y - mu) * rr);
    }
    {
      float2 v = *(const float2*)(a.atom_proj + (long)r * CC + lane * 2);
      float s = v.x + v.y, ss = v.x * v.x + v.y * v.y;
#pragma unroll
      for (int m = 1; m < 64; m <<= 1) { s += __shfl_xor(s, m); ss += __shfl_xor(ss, m); }
      float mu = s * (1.f / CC);
      float rr = rsqrtf(ss * (1.f / CC) - mu * mu + 1e-5f);
      float y0 = (v.x - mu) * rr, y1 = (v.y - mu) * rr;
      float2 wa = *(const float2*)(a.a_sln_w + lane * 2);
      float2 wt = *(const float2*)(a.t_sln_w + lane * 2);
      *(float2*)(a.s_ln_a + (long)r * CC + lane * 2) = make_float2(y0 * wa.x, y1 * wa.y);
      *(float2*)(a.s_ln_t + (long)r * CC + lane * 2) = make_float2(y0 * wt.x, y1 * wt.y);
    }
  }
}

__device__ __forceinline__ void ln2_stage(const Args& a, int bid, int tid) {
  int lane = tid & 63;
  for (int r = bid * 32 + (tid >> 6); r < bid * 32 + 32; r += 4) {
    float2 v = *(const float2*)(a.single2 + (long)r * CC + lane * 2);
    float s = v.x + v.y, ss = v.x * v.x + v.y * v.y;
#pragma unroll
    for (int m = 1; m < 64; m <<= 1) { s += __shfl_xor(s, m); ss += __shfl_xor(ss, m); }
    float mu = s * (1.f / CC);
    float rr = rsqrtf(ss * (1.f / CC) - mu * mu + 1e-5f);
    *(float2*)(a.ln_a2 + (long)r * CC + lane * 2) =
        make_float2((v.x - mu) * rr, (v.y - mu) * rr);
  }
}

__device__ __forceinline__ void adaln_stage(const Args& a, const float* A, const float* gw,
                                            const float* gb, const float* skw,
                                            const float* lnm, float* outp,
                                            int bid, int tid, float* sm) {
  int r0 = (bid & 31) * 64, c0 = (bid >> 5) * 64;
  float acc1[4][4] = {{0}}, acc2[4][4] = {{0}};
  gpair<true>(sm, tid, A, gw, 128, 128, 128, A, skw, 128, 128, 128, r0, c0, acc1, acc2);
  int tr = (tid >> 4) * 4, tc = (tid & 15) * 4;
#pragma unroll
  for (int i = 0; i < 4; ++i) {
    long r = r0 + tr + i;
    float4 lm = *(const float4*)(lnm + r * CC + c0 + tc);
    float lv[4] = {lm.x, lm.y, lm.z, lm.w};
    float o[4];
#pragma unroll
    for (int j = 0; j < 4; ++j)
      o[j] = sigm(acc1[i][j] + gb[c0 + tc + j]) * lv[j] + acc2[i][j];
    *(float4*)(outp + r * CC + c0 + tc) = make_float4(o[0], o[1], o[2], o[3]);
  }
}

__device__ __forceinline__ void gemm4_stage(const Args& a, int bid, int tid, float* sm) {
  int r0 = (bid & 31) * 64;
  int cg4 = (bid >> 5) * 64;
  int mat = cg4 >> 7;
  int c0 = cg4 & 127;
  const float* B = (mat == 0) ? a.wq : (mat == 1) ? a.wk : (mat == 2) ? a.wv : a.wg;
  float acc[4][4] = {{0}};
  gpair<false>(sm, tid, a.a_mat, B, 128, 128, 128, nullptr, nullptr, 0, 0, 0, r0, c0, acc, acc);
  float* outp = (mat == 0) ? a.qm : (mat == 1) ? a.km : (mat == 2) ? a.vm : a.gm;
  int tr = (tid >> 4) * 4, tc = (tid & 15) * 4;
#pragma unroll
  for (int i = 0; i < 4; ++i) {
    long r = r0 + tr + i;
    float o[4];
#pragma unroll
    for (int j = 0; j < 4; ++j) {
      float x = acc[i][j];
      if (mat == 0) x += a.bq[c0 + tc + j];
      if (mat == 3) x = sigm(x + a.bg[c0 + tc + j]);
      o[j] = x;
    }
    *(float4*)(outp + r * CC + c0 + tc) = make_float4(o[0], o[1], o[2], o[3]);
  }
}

__device__ __forceinline__ void attn_unit(const Args& a, int u, int tid, float* sm) {
  __syncthreads();  // protect smem reuse
  int w = u & 63, h = u >> 6;
  int q0 = w * 32, k0 = w * 32 - 48;
  float* Qs = sm;          // [32][17]
  float* Ks = sm + 544;    // [128][20]
  float* Vs = sm + 3104;   // [128][20]
  float* Ps = sm + 5664;   // [32][132]
  for (int i = tid; i < 32 * 16; i += 256) {
    int qi = i >> 4, d = i & 15;
    Qs[qi * 17 + d] = a.qm[(long)(q0 + qi) * CC + h * DD + d];
  }
  for (int i = tid; i < 128 * 16; i += 256) {
    int kk = i >> 4, d = i & 15;
    int k = k0 + kk;
    bool ok = (k >= 0 && k < NN);
    Ks[kk * 20 + d] = ok ? a.km[(long)k * CC + h * DD + d] : 0.f;
    Vs[kk * 20 + d] = ok ? a.vm[(long)k * CC + h * DD + d] : 0.f;
  }
  __syncthreads();
  int qi = tid >> 3, kg = tid & 7;
  const float* brow = a.bias + (long)h * NN * NKEY + (long)(q0 + qi) * NKEY;
  float qreg[16];
#pragma unroll
  for (int d = 0; d < 16; ++d) qreg[d] = Qs[qi * 17 + d];
  float l[16];
#pragma unroll
  for (int j = 0; j < 16; ++j) {
    int kk = kg + 8 * j;
    const float4* kr = (const float4*)&Ks[kk * 20];
    float4 k0v = kr[0], k1v = kr[1], k2v = kr[2], k3v = kr[3];
    float acc = 0.f;
    acc = fmaf(qreg[0], k0v.x, acc);  acc = fmaf(qreg[1], k0v.y, acc);
    acc = fmaf(qreg[2], k0v.z, acc);  acc = fmaf(qreg[3], k0v.w, acc);
    acc = fmaf(qreg[4], k1v.x, acc);  acc = fmaf(qreg[5], k1v.y, acc);
    acc = fmaf(qreg[6], k1v.z, acc);  acc = fmaf(qreg[7], k1v.w, acc);
    acc = fmaf(qreg[8], k2v.x, acc);  acc = fmaf(qreg[9], k2v.y, acc);
    acc = fmaf(qreg[10], k2v.z, acc); acc = fmaf(qreg[11], k2v.w, acc);
    acc = fmaf(qreg[12], k3v.x, acc); acc = fmaf(qreg[13], k3v.y, acc);
    acc = fmaf(qreg[14], k3v.z, acc); acc = fmaf(qreg[15], k3v.w, acc);
    l[j] = acc * 0.25f + brow[kk];
  }
  float m = l[0];
#pragma unroll
  for (int j = 1; j < 16; ++j) m = fmaxf(m, l[j]);
#pragma unroll
  for (int mm = 1; mm < 8; mm <<= 1) m = fmaxf(m, __shfl_xor(m, mm));
  float sum = 0.f;
#pragma unroll
  for (int j = 0; j < 16; ++j) { l[j] = expf(l[j] - m); sum += l[j]; }
#pragma unroll
  for (int mm = 1; mm < 8; mm <<= 1) sum += __shfl_xor(sum, mm);
  float inv = 1.f / sum;
#pragma unroll
  for (int j = 0; j < 16; ++j) Ps[qi * 132 + kg + 8 * j] = l[j] * inv;
  __syncthreads();
  int d0 = tid & 7;
  float o0 = 0.f, o1 = 0.f;
  for (int kk = 0; kk < 128; ++kk) {
    float p = Ps[qi * 132 + kk];
    o0 = fmaf(p, Vs[kk * 20 + d0], o0);
    o1 = fmaf(p, Vs[kk * 20 + d0 + 8], o1);
  }
  long base = (long)(q0 + qi) * CC + h * DD;
  a.ogm[base + d0] = o0 * a.gm[base + d0];
  a.ogm[base + d0 + 8] = o1 * a.gm[base + d0 + 8];
}

__device__ __forceinline__ void out1_stage(const Args& a, int bid, int tid, float* sm) {
  int r0 = (bid & 31) * 64, c0 = (bid >> 5) * 64;
  float accX[4][4] = {{0}}, accW[4][4] = {{0}};
  gpair<true>(sm, tid, a.ogm, a.wo, 128, 128, 128, a.atom_proj, a.wog, 128, 128, 128,
              r0, c0, accX, accW);
  int tr = (tid >> 4) * 4, tc = (tid & 15) * 4;
#pragma unroll
  for (int i = 0; i < 4; ++i) {
    long r = r0 + tr + i;
    float4 sv = *(const float4*)(a.atom_single + r * CC + c0 + tc);
    float s[4] = {sv.x, sv.y, sv.z, sv.w};
    float o[4];
#pragma unroll
    for (int j = 0; j < 4; ++j) {
      int c = c0 + tc + j;
      o[j] = s[j] + sigm(accW[i][j] + a.bog[c]) * (accX[i][j] + a.bo[c]);
    }
    *(float4*)(a.single2 + r * CC + c0 + tc) = make_float4(o[0], o[1], o[2], o[3]);
  }
}

__device__ __forceinline__ void swiglu_stage(const Args& a, int bid, int tid, float* sm) {
  int r0 = (bid & 31) * 64, c0 = (bid >> 5) * 64;
  float acc1[4][4] = {{0}}, acc2[4][4] = {{0}};
  gpair<true>(sm, tid, a.t_mat, a.w_sw, 128, 256, 128, a.t_mat, a.w_hid, 128, 256, 128,
              r0, c0, acc1, acc2);
  int tr = (tid >> 4) * 4, tc = (tid & 15) * 4;
#pragma unroll
  for (int i = 0; i < 4; ++i) {
    long r = r0 + tr + i;
    float o[4];
#pragma unroll
    for (int j = 0; j < 4; ++j) {
      float x = acc1[i][j];
      o[j] = x * sigm(x) * acc2[i][j];
    }
    *(float4*)(a.hidden + r * 256 + c0 + tc) = make_float4(o[0], o[1], o[2], o[3]);
  }
}

__device__ __forceinline__ void out2_stage(const Args& a, int bid, int tid, float* sm) {
  int r0 = (bid & 31) * 64, c0 = (bid >> 5) * 64;
  float accX[4][4] = {{0}}, accW[4][4] = {{0}};
  gpair<true>(sm, tid, a.hidden, a.w_out, 256, 128, 256, a.atom_proj, a.t_wog, 128, 128, 128,
              r0, c0, accX, accW);
  int tr = (tid >> 4) * 4, tc = (tid & 15) * 4;
#pragma unroll
  for (int i = 0; i < 4; ++i) {
    long r = r0 + tr + i;
    float4 sv = *(const float4*)(a.single2 + r * CC + c0 + tc);
    float s[4] = {sv.x, sv.y, sv.z, sv.w};
    float o[4];
#pragma unroll
    for (int j = 0; j < 4; ++j) {
      int c = c0 + tc + j;
      o[j] = s[j] + sigm(accW[i][j] + a.t_bog[c]) * accX[i][j];
    }
    *(float4*)(a.out + r * CC + c0 + tc) = make_float4(o[0], o[1], o[2], o[3]);
  }
}

// ---------------------------------------------------------------------------
// Persistent cooperative mega-kernel: 9 stages, copy interleaved everywhere.
// ---------------------------------------------------------------------------
__global__ __launch_bounds__(256) void mega(Args a) {
  cg::grid_group grid = cg::this_grid();
  __shared__ __align__(16) float sm[9888];
  int bid = blockIdx.x, tid = threadIdx.x;

  // S0: bias (0..95) + ln1 (96..127) + copy (128..255)
  if (bid < 96) bias_stage(a, bid, tid, sm);
  else if (bid < 128) ln1_stage(a, bid - 96, tid);
  else copy_stage(a, 0, bid - 128, 128, tid);
  grid.sync();

  // S1: adaln-a (0..63) + copy
  if (bid < 64) adaln_stage(a, a.s_ln_a, a.a_gate_w, a.a_gate_b, a.a_skip_w, a.ln_as, a.a_mat, bid, tid, sm);
  else copy_stage(a, 1, bid - 64, 192, tid);
  grid.sync();

  // S2: qkvg (all) then copy (all)
  gemm4_stage(a, bid, tid, sm);
  copy_stage(a, 2, bid, 256, tid);
  grid.sync();

  // S3: attention (all, 2 units each) then copy (all)
  attn_unit(a, bid, tid, sm);
  attn_unit(a, bid + 256, tid, sm);
  copy_stage(a, 3, bid, 256, tid);
  grid.sync();

  // S4: out1 (0..63) + copy
  if (bid < 64) out1_stage(a, bid, tid, sm);
  else copy_stage(a, 4, bid - 64, 192, tid);
  grid.sync();

  // S5: ln2 (0..63) + copy
  if (bid < 64) ln2_stage(a, bid, tid);
  else copy_stage(a, 5, bid - 64, 192, tid);
  grid.sync();

  // S6: adaln-t (0..63) + copy
  if (bid < 64) adaln_stage(a, a.s_ln_t, a.t_gate_w, a.t_gate_b, a.t_skip_w, a.ln_a2, a.t_mat, bid, tid, sm);
  else copy_stage(a, 6, bid - 64, 192, tid);
  grid.sync();

  // S7: swiglu (0..127) + copy
  if (bid < 128) swiglu_stage(a, bid, tid, sm);
  else copy_stage(a, 7, bid - 128, 128, tid);
  grid.sync();

  // S8: out2 (0..63) + copy
  if (bid < 64) out2_stage(a, bid, tid, sm);
  else copy_stage(a, 8, bid - 64, 192, tid);
}

// ---------------------------------------------------------------------------
// Fallback discrete kernels (used only if cooperative launch is unavailable).
// ---------------------------------------------------------------------------
__global__ __launch_bounds__(256) void fb_copy(Args a) {
  const float4* proj4 = (const float4*)a.atom_proj;
  const float4* pair4 = (const float4*)a.atom_pair;
  float4* dst = (float4*)(a.out + (long)NN * CC);
  for (long i = (long)blockIdx.x * 256 + threadIdx.x; i < NCPTOT;
       i += (long)gridDim.x * 256)
    dst[i] = (i < NPR) ? proj4[i] : pair4[i - NPR];
}
__global__ __launch_bounds__(256) void fb_s0(Args a) {
  __shared__ __align__(16) float sm[9888];
  if (blockIdx.x < 96) bias_stage(a, blockIdx.x, threadIdx.x, sm);
  else ln1_stage(a, blockIdx.x - 96, threadIdx.x);
}
__global__ __launch_bounds__(256) void fb_s1(Args a) {
  __shared__ __align__(16) float sm[9888];
  adaln_stage(a, a.s_ln_a, a.a_gate_w, a.a_gate_b, a.a_skip_w, a.ln_as, a.a_mat,
              blockIdx.x, threadIdx.x, sm);
}
__global__ __launch_bounds__(256) void fb_s2(Args a) {
  __shared__ __align__(16) float sm[9888];
  gemm4_stage(a, blockIdx.x, threadIdx.x, sm);
}
__global__ __launch_bounds__(256) void fb_s3(Args a) {
  __shared__ __align__(16) float sm[9888];
  attn_unit(a, blockIdx.x, threadIdx.x, sm);
}
__global__ __launch_bounds__(256) void fb_s4(Args a) {
  __shared__ __align__(16) float sm[9888];
  out1_stage(a, blockIdx.x, threadIdx.x, sm);
}
__global__ __launch_bounds__(256) void fb_s5(Args a) {
  ln2_stage(a, blockIdx.x, threadIdx.x);
}
__global__ __launch_bounds__(256) void fb_s6(Args a) {
  __shared__ __align__(16) float sm[9888];
  adaln_stage(a, a.s_ln_t, a.t_gate_w, a.t_gate_b, a.t_skip_w, a.ln_a2, a.t_mat,
              blockIdx.x, threadIdx.x, sm);
}
__global__ __launch_bounds__(256) void fb_s7(Args a) {
  __shared__ __align__(16) float sm[9888];
  swiglu_stage(a, blockIdx.x, threadIdx.x, sm);
}
__global__ __launch_bounds__(256) void fb_s8(Args a) {
  __shared__ __align__(16) float sm[9888];
  out2_stage(a, blockIdx.x, threadIdx.x, sm);
}

// ---------------------------------------------------------------------------
extern "C" void kernel_launch(void* const* d_in, const int* in_sizes, int n_in,
                              void* d_out, int out_size, void* d_ws, size_t ws_size,
                              hipStream_t stream) {
  (void)in_sizes; (void)n_in; (void)out_size; (void)ws_size;
  Args a;
  a.atom_single = (const float*)d_in[0];
  a.atom_proj   = (const float*)d_in[1];
  a.atom_pair   = (const float*)d_in[2];
  a.mask        = (const float*)d_in[3];
  a.a_sln_w  = (const float*)d_in[4];
  a.a_gate_w = (const float*)d_in[5];
  a.a_gate_b = (const float*)d_in[6];
  a.a_skip_w = (const float*)d_in[7];
  a.wq = (const float*)d_in[8];  a.bq = (const float*)d_in[9];
  a.wk = (const float*)d_in[10]; a.wv = (const float*)d_in[11];
  a.wg = (const float*)d_in[12]; a.bg = (const float*)d_in[13];
  a.wo = (const float*)d_in[14]; a.bo = (const float*)d_in[15];
  a.lnz_w = (const float*)d_in[16]; a.lnz_b = (const float*)d_in[17];
  a.wz = (const float*)d_in[18];
  a.wog = (const float*)d_in[19]; a.bog = (const float*)d_in[20];
  a.t_sln_w  = (const float*)d_in[21];
  a.t_gate_w = (const float*)d_in[22];
  a.t_gate_b = (const float*)d_in[23];
  a.t_skip_w = (const float*)d_in[24];
  a.w_sw  = (const float*)d_in[25];
  a.w_hid = (const float*)d_in[26];
  a.w_out = (const float*)d_in[27];
  a.t_wog = (const float*)d_in[28];
  a.t_bog = (const float*)d_in[29];
  a.out = (float*)d_out;

  float* ws = (float*)d_ws;
  const long NC = (long)NN * CC;
  a.s_ln_a  = ws + 0 * NC;
  a.s_ln_t  = ws + 1 * NC;
  a.ln_as   = ws + 2 * NC;
  a.a_mat   = ws + 3 * NC;
  a.qm      = ws + 4 * NC;
  a.km      = ws + 5 * NC;
  a.vm      = ws + 6 * NC;
  a.gm      = ws + 7 * NC;
  a.ogm     = ws + 8 * NC;
  a.single2 = ws + 9 * NC;
  a.ln_a2   = ws + 10 * NC;
  a.t_mat   = ws + 11 * NC;
  a.hidden  = ws + 12 * NC;   // N*256 = 2*NC
  a.bias    = ws + 14 * NC;   // H*N*128 = 8*NC

  // Copy-share cut points (per-stage slices of the passthrough copy),
  // skewed away from the all-block compute stages S2/S3.
  const int cum[10] = {0, 2, 7, 9, 11, 16, 22, 27, 31, 36};
  for (int i = 0; i < 10; ++i) a.cut[i] = NCPTOT * (long)cum[i] / 36;

  void* params[] = {(void*)&a};
  hipError_t err = hipLaunchCooperativeKernel((const void*)mega, dim3(256), dim3(256),
                                              params, 0, stream);
  if (err != hipSuccess) {
    (void)hipGetLastError();
    fb_copy<<<2048, 256, 0, stream>>>(a);
    fb_s0<<<128, 256, 0, stream>>>(a);
    fb_s1<<<64, 256, 0, stream>>>(a);
    fb_s2<<<256, 256, 0, stream>>>(a);
    fb_s3<<<512, 256, 0, stream>>>(a);
    fb_s4<<<64, 256, 0, stream>>>(a);
    fb_s5<<<64, 256, 0, stream>>>(a);
    fb_s6<<<64, 256, 0, stream>>>(a);
    fb_s7<<<128, 256, 0, stream>>>(a);
    fb_s8<<<64, 256, 0, stream>>>(a);
  }
}